// Round 1
// baseline (423.683 us; speedup 1.0000x reference)
//
#include <hip/hip_runtime.h>
#include <hip/hip_bf16.h>
#include <math.h>

// Problem constants (Mask2Former pixel decoder / MS-deformable attention)
#define BB 4
#define SEQ 5376
#define DD 256
#define NH 8
#define NL 3
#define NP 4
#define DH 32
#define MTOT (BB * SEQ)          // 21504 rows for all GEMMs

// ---------------------------------------------------------------------------
// hs = hidden + pos (elementwise, float4)
// ---------------------------------------------------------------------------
__global__ void add_kernel(const float4* __restrict__ a, const float4* __restrict__ b,
                           float4* __restrict__ c, int n4) {
    int i = blockIdx.x * blockDim.x + threadIdx.x;
    int stride = gridDim.x * blockDim.x;
    for (; i < n4; i += stride) {
        float4 x = a[i], y = b[i];
        c[i] = make_float4(x.x + y.x, x.y + y.y, x.z + y.z, x.w + y.w);
    }
}

// ---------------------------------------------------------------------------
// Simple tiled fp32 GEMM: C[M,N] = A[M,K] @ W[K,N] + bias[N]
// BM=BN=64, BK=16, 256 threads, 4x4 per thread. M % 64 == 0 assumed; N guarded.
// ---------------------------------------------------------------------------
__global__ __launch_bounds__(256) void gemm_bias(
    const float* __restrict__ A, const float* __restrict__ W,
    const float* __restrict__ bias, float* __restrict__ C,
    int M, int N, int K) {
    const int BM = 64, BN = 64, BK = 16;
    __shared__ float As[BK][BM + 1];
    __shared__ float Ws[BK][BN];
    int bm = blockIdx.y * BM;
    int bn = blockIdx.x * BN;
    int tid = threadIdx.x;
    int tx = tid & 15, ty = tid >> 4;
    float acc[4][4] = {};
    for (int k0 = 0; k0 < K; k0 += BK) {
        // A tile: 64x16 = 1024 elems
        #pragma unroll
        for (int e = tid; e < BM * BK; e += 256) {
            int m = e >> 4;
            int k = e & 15;
            As[k][m] = A[(size_t)(bm + m) * K + k0 + k];
        }
        // W tile: 16x64 = 1024 elems
        #pragma unroll
        for (int e = tid; e < BK * BN; e += 256) {
            int k = e >> 6;
            int n = e & 63;
            int gn = bn + n;
            Ws[k][n] = (gn < N) ? W[(size_t)(k0 + k) * N + gn] : 0.0f;
        }
        __syncthreads();
        #pragma unroll
        for (int k = 0; k < BK; ++k) {
            float a[4], w[4];
            #pragma unroll
            for (int i = 0; i < 4; i++) a[i] = As[k][ty * 4 + i];
            #pragma unroll
            for (int j = 0; j < 4; j++) w[j] = Ws[k][tx * 4 + j];
            #pragma unroll
            for (int i = 0; i < 4; i++)
                #pragma unroll
                for (int j = 0; j < 4; j++)
                    acc[i][j] += a[i] * w[j];
        }
        __syncthreads();
    }
    #pragma unroll
    for (int i = 0; i < 4; i++) {
        int gm = bm + ty * 4 + i;
        #pragma unroll
        for (int j = 0; j < 4; j++) {
            int gn = bn + tx * 4 + j;
            if (gn < N) C[(size_t)gm * N + gn] = acc[i][j] + bias[gn];
        }
    }
}

// ---------------------------------------------------------------------------
// Softmax over 12 logits per (b,q,h). One thread each.
// ---------------------------------------------------------------------------
__global__ void softmax12(const float* __restrict__ logits, float* __restrict__ attn,
                          int total) {
    int i = blockIdx.x * blockDim.x + threadIdx.x;
    if (i >= total) return;
    const float* p = logits + (size_t)i * 12;
    float m = -INFINITY;
    float v[12];
    #pragma unroll
    for (int j = 0; j < 12; j++) { v[j] = p[j]; m = fmaxf(m, v[j]); }
    float s = 0.f;
    #pragma unroll
    for (int j = 0; j < 12; j++) { v[j] = expf(v[j] - m); s += v[j]; }
    float inv = 1.0f / s;
    float* o = attn + (size_t)i * 12;
    #pragma unroll
    for (int j = 0; j < 12; j++) o[j] = v[j] * inv;
}

// ---------------------------------------------------------------------------
// Deformable sampling. One block per (b,q), 256 threads = (h in 0..7, d in 0..31).
// value:   (B,SEQ,256)  channel = h*32+d
// off:     (B,SEQ,192)  idx = h*24 + l*8 + p*2 + c
// attn:    (B,SEQ,96)   idx = h*12 + l*4 + p
// refp:    (B,SEQ,NL,2)
// out:     (B,SEQ,256)
// ---------------------------------------------------------------------------
__global__ __launch_bounds__(256) void msda_sample(
    const float* __restrict__ value, const float* __restrict__ off,
    const float* __restrict__ attn, const float* __restrict__ refp,
    float* __restrict__ out) {
    int bq = blockIdx.x;
    int tid = threadIdx.x;
    int h = tid >> 5;
    int d = tid & 31;
    int b = bq / SEQ;

    const float* offp = off + (size_t)bq * 192 + h * 24;
    const float* ap   = attn + (size_t)bq * 96 + h * 12;
    const float* rp   = refp + (size_t)bq * 6;
    const float* vbase = value + ((size_t)b * SEQ) * 256 + h * 32 + d;

    const int Hs[3]  = {64, 32, 16};
    const int Wls[3] = {64, 32, 16};
    const int st[3]  = {0, 4096, 5120};

    float acc = 0.0f;
    #pragma unroll
    for (int l = 0; l < 3; l++) {
        float rx = rp[l * 2 + 0];
        float ry = rp[l * 2 + 1];
        int Hl = Hs[l], Wl = Wls[l];
        const float* vl = vbase + (size_t)st[l] * 256;
        float fW = (float)Wl, fH = (float)Hl;
        #pragma unroll
        for (int p = 0; p < 4; p++) {
            float aw = ap[l * 4 + p];
            float ox = offp[l * 8 + p * 2 + 0];
            float oy = offp[l * 8 + p * 2 + 1];
            // x = loc_x * W - 0.5, loc_x = rx + ox/W
            float x = (rx + ox / fW) * fW - 0.5f;
            float y = (ry + oy / fH) * fH - 0.5f;
            float x0f = floorf(x), y0f = floorf(y);
            float wx = x - x0f, wy = y - y0f;
            int x0 = (int)x0f, y0 = (int)y0f;
            int x1 = x0 + 1, y1 = y0 + 1;
            bool vx0 = (x0 >= 0) & (x0 < Wl);
            bool vx1 = (x1 >= 0) & (x1 < Wl);
            bool vy0 = (y0 >= 0) & (y0 < Hl);
            bool vy1 = (y1 >= 0) & (y1 < Hl);
            float v = 0.0f;
            if (vx0 & vy0) v += vl[(size_t)(y0 * Wl + x0) * 256] * (1.f - wx) * (1.f - wy);
            if (vx1 & vy0) v += vl[(size_t)(y0 * Wl + x1) * 256] * wx * (1.f - wy);
            if (vx0 & vy1) v += vl[(size_t)(y1 * Wl + x0) * 256] * (1.f - wx) * wy;
            if (vx1 & vy1) v += vl[(size_t)(y1 * Wl + x1) * 256] * wx * wy;
            acc += aw * v;
        }
    }
    out[(size_t)bq * 256 + h * 32 + d] = acc;
}

// ---------------------------------------------------------------------------
extern "C" void kernel_launch(void* const* d_in, const int* in_sizes, int n_in,
                              void* d_out, int out_size, void* d_ws, size_t ws_size,
                              hipStream_t stream) {
    const float* hidden = (const float*)d_in[0];
    const float* pos    = (const float*)d_in[1];
    const float* refp   = (const float*)d_in[2];
    const float* Wv     = (const float*)d_in[3];
    const float* bv     = (const float*)d_in[4];
    const float* Wo     = (const float*)d_in[5];
    const float* bo     = (const float*)d_in[6];
    const float* Wa     = (const float*)d_in[7];
    const float* ba     = (const float*)d_in[8];
    const float* Wout   = (const float*)d_in[9];
    const float* bout   = (const float*)d_in[10];

    float* out      = (float*)d_out;                       // (B,SEQ,256)
    float* attn_out = out + (size_t)BB * SEQ * DD;         // (B,SEQ,NH,NL,NP)

    const size_t BSD = (size_t)BB * SEQ * DD;              // 5,505,024
    float* ws      = (float*)d_ws;
    float* hs      = ws;                                   // B*SEQ*256
    float* value   = hs + BSD;                             // B*SEQ*256
    float* offbuf  = value + BSD;                          // B*SEQ*192
    float* logits  = offbuf + (size_t)BB * SEQ * 192;      // B*SEQ*96
    float* sampled = logits + (size_t)BB * SEQ * 96;       // B*SEQ*256

    // 1. hs = hidden + pos
    {
        int n4 = (int)(BSD / 4);
        int blocks = min((n4 + 255) / 256, 2048);
        add_kernel<<<blocks, 256, 0, stream>>>((const float4*)hidden, (const float4*)pos,
                                               (float4*)hs, n4);
    }
    // 2. value = hidden @ Wv + bv   (M=21504, N=256, K=256)
    {
        dim3 grid(DD / 64, MTOT / 64);
        gemm_bias<<<grid, 256, 0, stream>>>(hidden, Wv, bv, value, MTOT, DD, DD);
    }
    // 3. off = hs @ Wo + bo  (N=192)
    {
        dim3 grid(192 / 64, MTOT / 64);
        gemm_bias<<<grid, 256, 0, stream>>>(hs, Wo, bo, offbuf, MTOT, 192, DD);
    }
    // 4. logits = hs @ Wa + ba  (N=96 -> 2 col-blocks, guarded)
    {
        dim3 grid((96 + 63) / 64, MTOT / 64);
        gemm_bias<<<grid, 256, 0, stream>>>(hs, Wa, ba, logits, MTOT, 96, DD);
    }
    // 5. softmax over 12 -> attn output region of d_out
    {
        int total = BB * SEQ * NH;
        softmax12<<<(total + 255) / 256, 256, 0, stream>>>(logits, attn_out, total);
    }
    // 6. deformable bilinear sampling -> sampled (B,SEQ,256)
    {
        msda_sample<<<BB * SEQ, 256, 0, stream>>>(value, offbuf, attn_out, refp, sampled);
    }
    // 7. out = sampled @ Wout + bout -> d_out
    {
        dim3 grid(DD / 64, MTOT / 64);
        gemm_bias<<<grid, 256, 0, stream>>>(sampled, Wout, bout, out, MTOT, DD, DD);
    }
}

// Round 2
// 325.490 us; speedup vs baseline: 1.3017x; 1.3017x over previous
//
#include <hip/hip_runtime.h>
#include <hip/hip_bf16.h>
#include <math.h>

// Problem constants (Mask2Former pixel decoder / MS-deformable attention)
#define BB 4
#define SEQ 5376
#define DD 256
#define NH 8
#define NL 3
#define NP 4
#define DH 32
#define MTOT (BB * SEQ)          // 21504 rows for all GEMMs

// ---------------------------------------------------------------------------
// Tiled fp32 GEMM: C[M,N] = A[M,K] @ W[K,N] + bias[N]
// BM=BN=64, BK=16, 256 threads, 4x4 per thread. M % 64 == 0 assumed; N guarded.
// A2 != nullptr -> A-tile = A[..] + A2[..] (fused elementwise add)
// ---------------------------------------------------------------------------
__global__ __launch_bounds__(256) void gemm_bias(
    const float* __restrict__ A, const float* __restrict__ A2,
    const float* __restrict__ W,
    const float* __restrict__ bias, float* __restrict__ C,
    int M, int N, int K) {
    const int BM = 64, BN = 64, BK = 16;
    __shared__ float As[BK][BM + 1];
    __shared__ float Ws[BK][BN];
    int bm = blockIdx.y * BM;
    int bn = blockIdx.x * BN;
    int tid = threadIdx.x;
    int tx = tid & 15, ty = tid >> 4;
    float acc[4][4] = {};
    for (int k0 = 0; k0 < K; k0 += BK) {
        // A tile: 64x16 = 1024 elems
        #pragma unroll
        for (int e = tid; e < BM * BK; e += 256) {
            int m = e >> 4;
            int k = e & 15;
            size_t gi = (size_t)(bm + m) * K + k0 + k;
            float v = A[gi];
            if (A2) v += A2[gi];
            As[k][m] = v;
        }
        // W tile: 16x64 = 1024 elems
        #pragma unroll
        for (int e = tid; e < BK * BN; e += 256) {
            int k = e >> 6;
            int n = e & 63;
            int gn = bn + n;
            Ws[k][n] = (gn < N) ? W[(size_t)(k0 + k) * N + gn] : 0.0f;
        }
        __syncthreads();
        #pragma unroll
        for (int k = 0; k < BK; ++k) {
            float a[4], w[4];
            #pragma unroll
            for (int i = 0; i < 4; i++) a[i] = As[k][ty * 4 + i];
            #pragma unroll
            for (int j = 0; j < 4; j++) w[j] = Ws[k][tx * 4 + j];
            #pragma unroll
            for (int i = 0; i < 4; i++)
                #pragma unroll
                for (int j = 0; j < 4; j++)
                    acc[i][j] += a[i] * w[j];
        }
        __syncthreads();
    }
    #pragma unroll
    for (int i = 0; i < 4; i++) {
        int gm = bm + ty * 4 + i;
        #pragma unroll
        for (int j = 0; j < 4; j++) {
            int gn = bn + tx * 4 + j;
            if (gn < N) C[(size_t)gm * N + gn] = acc[i][j] + bias[gn];
        }
    }
}

// ---------------------------------------------------------------------------
// Softmax over 12 logits per (b,q,h). One thread each.
// ---------------------------------------------------------------------------
__global__ void softmax12(const float* __restrict__ logits, float* __restrict__ attn,
                          int total) {
    int i = blockIdx.x * blockDim.x + threadIdx.x;
    if (i >= total) return;
    const float* p = logits + (size_t)i * 12;
    float m = -INFINITY;
    float v[12];
    #pragma unroll
    for (int j = 0; j < 12; j++) { v[j] = p[j]; m = fmaxf(m, v[j]); }
    float s = 0.f;
    #pragma unroll
    for (int j = 0; j < 12; j++) { v[j] = expf(v[j] - m); s += v[j]; }
    float inv = 1.0f / s;
    float* o = attn + (size_t)i * 12;
    #pragma unroll
    for (int j = 0; j < 12; j++) o[j] = v[j] * inv;
}

// ---------------------------------------------------------------------------
// Deformable sampling, vectorized over channels.
// 256 threads/block = 4 queries; each wave (64 lanes) = one query:
//   lane = h*8 + d4  (h in 0..7 heads, d4 in 0..7 float4 channel-groups)
// value viewed as float4: row stride 64 (= 256 floats).
// ---------------------------------------------------------------------------
__global__ __launch_bounds__(256) void msda_sample_v2(
    const float4* __restrict__ value, const float* __restrict__ off,
    const float* __restrict__ attn, const float* __restrict__ refp,
    float4* __restrict__ out) {
    int wave = threadIdx.x >> 6;
    int lane = threadIdx.x & 63;
    int bq = blockIdx.x * 4 + wave;
    int h = lane >> 3;
    int d4 = lane & 7;
    int b = bq / SEQ;

    const float* offp = off + (size_t)bq * 192 + h * 24;
    const float* ap   = attn + (size_t)bq * 96 + h * 12;
    const float* rp   = refp + (size_t)bq * 6;
    const float4* vbase = value + ((size_t)b * SEQ) * 64 + h * 8 + d4;

    const int Hs[3] = {64, 32, 16};
    const int st[3] = {0, 4096, 5120};

    float4 acc = make_float4(0.f, 0.f, 0.f, 0.f);
    #pragma unroll
    for (int l = 0; l < 3; l++) {
        int Wl = Hs[l], Hl = Hs[l];           // square levels here
        float fW = (float)Wl, fH = (float)Hl;
        float rxW = rp[l * 2 + 0] * fW;
        float ryH = rp[l * 2 + 1] * fH;
        const float4* vl = vbase + (size_t)st[l] * 64;
        #pragma unroll
        for (int p = 0; p < 4; p++) {
            float aw = ap[l * 4 + p];
            float ox = offp[l * 8 + p * 2 + 0];
            float oy = offp[l * 8 + p * 2 + 1];
            float x = rxW + ox - 0.5f;
            float y = ryH + oy - 0.5f;
            float x0f = floorf(x), y0f = floorf(y);
            float wx = x - x0f, wy = y - y0f;
            int x0 = (int)x0f, y0 = (int)y0f;
            int x1 = x0 + 1, y1 = y0 + 1;
            float vx0 = (x0 >= 0 && x0 < Wl) ? 1.f : 0.f;
            float vx1 = (x1 >= 0 && x1 < Wl) ? 1.f : 0.f;
            float vy0 = (y0 >= 0 && y0 < Hl) ? 1.f : 0.f;
            float vy1 = (y1 >= 0 && y1 < Hl) ? 1.f : 0.f;
            int xc0 = min(max(x0, 0), Wl - 1);
            int xc1 = min(max(x1, 0), Wl - 1);
            int yc0 = min(max(y0, 0), Hl - 1);
            int yc1 = min(max(y1, 0), Hl - 1);
            float w00 = aw * (1.f - wx) * (1.f - wy) * vx0 * vy0;
            float w01 = aw * wx * (1.f - wy) * vx1 * vy0;
            float w10 = aw * (1.f - wx) * wy * vx0 * vy1;
            float w11 = aw * wx * wy * vx1 * vy1;
            float4 t00 = vl[(size_t)(yc0 * Wl + xc0) * 64];
            float4 t01 = vl[(size_t)(yc0 * Wl + xc1) * 64];
            float4 t10 = vl[(size_t)(yc1 * Wl + xc0) * 64];
            float4 t11 = vl[(size_t)(yc1 * Wl + xc1) * 64];
            acc.x = fmaf(w00, t00.x, fmaf(w01, t01.x, fmaf(w10, t10.x, fmaf(w11, t11.x, acc.x))));
            acc.y = fmaf(w00, t00.y, fmaf(w01, t01.y, fmaf(w10, t10.y, fmaf(w11, t11.y, acc.y))));
            acc.z = fmaf(w00, t00.z, fmaf(w01, t01.z, fmaf(w10, t10.z, fmaf(w11, t11.z, acc.z))));
            acc.w = fmaf(w00, t00.w, fmaf(w01, t01.w, fmaf(w11, t11.w, fmaf(w10, t10.w, acc.w))));
        }
    }
    out[(size_t)bq * 64 + h * 8 + d4] = acc;
}

// ---------------------------------------------------------------------------
extern "C" void kernel_launch(void* const* d_in, const int* in_sizes, int n_in,
                              void* d_out, int out_size, void* d_ws, size_t ws_size,
                              hipStream_t stream) {
    const float* hidden = (const float*)d_in[0];
    const float* pos    = (const float*)d_in[1];
    const float* refp   = (const float*)d_in[2];
    const float* Wv     = (const float*)d_in[3];
    const float* bv     = (const float*)d_in[4];
    const float* Wo     = (const float*)d_in[5];
    const float* bo     = (const float*)d_in[6];
    const float* Wa     = (const float*)d_in[7];
    const float* ba     = (const float*)d_in[8];
    const float* Wout   = (const float*)d_in[9];
    const float* bout   = (const float*)d_in[10];

    float* out      = (float*)d_out;                       // (B,SEQ,256)
    float* attn_out = out + (size_t)BB * SEQ * DD;         // (B,SEQ,NH,NL,NP)

    const size_t BSD = (size_t)BB * SEQ * DD;              // 5,505,024
    float* ws      = (float*)d_ws;
    float* value   = ws;                                   // B*SEQ*256
    float* offbuf  = value + BSD;                          // B*SEQ*192
    float* logits  = offbuf + (size_t)BB * SEQ * 192;      // B*SEQ*96
    float* sampled = logits + (size_t)BB * SEQ * 96;       // B*SEQ*256

    // 1. value = hidden @ Wv + bv   (M=21504, N=256, K=256)
    {
        dim3 grid(DD / 64, MTOT / 64);
        gemm_bias<<<grid, 256, 0, stream>>>(hidden, nullptr, Wv, bv, value, MTOT, DD, DD);
    }
    // 2. off = (hidden+pos) @ Wo + bo  (N=192)  -- add fused into A-tile load
    {
        dim3 grid(192 / 64, MTOT / 64);
        gemm_bias<<<grid, 256, 0, stream>>>(hidden, pos, Wo, bo, offbuf, MTOT, 192, DD);
    }
    // 3. logits = (hidden+pos) @ Wa + ba  (N=96 -> 2 col-blocks, guarded)
    {
        dim3 grid((96 + 63) / 64, MTOT / 64);
        gemm_bias<<<grid, 256, 0, stream>>>(hidden, pos, Wa, ba, logits, MTOT, 96, DD);
    }
    // 4. softmax over 12 -> attn output region of d_out
    {
        int total = BB * SEQ * NH;
        softmax12<<<(total + 255) / 256, 256, 0, stream>>>(logits, attn_out, total);
    }
    // 5. deformable bilinear sampling -> sampled (B,SEQ,256)
    {
        msda_sample_v2<<<MTOT / 4, 256, 0, stream>>>((const float4*)value, offbuf,
                                                     attn_out, refp, (float4*)sampled);
    }
    // 6. out = sampled @ Wout + bout -> d_out
    {
        dim3 grid(DD / 64, MTOT / 64);
        gemm_bias<<<grid, 256, 0, stream>>>(sampled, nullptr, Wout, bout, out, MTOT, DD, DD);
    }
}

// Round 3
// 116.673 us; speedup vs baseline: 3.6314x; 2.7898x over previous
//
#include <hip/hip_runtime.h>
#include <hip/hip_bf16.h>
#include <math.h>

// Problem constants (Mask2Former pixel decoder / MS-deformable attention)
#define BB 4
#define SEQ 5376
#define DD 256
#define NH 8
#define NL 3
#define NP 4
#define DH 32
#define MTOT (BB * SEQ)          // 21504 rows for all GEMMs

typedef __attribute__((ext_vector_type(8))) short bf16x8;
typedef __attribute__((ext_vector_type(4))) float f32x4;

__device__ __forceinline__ ushort f2b(float f) {
    __hip_bfloat16 h = __float2bfloat16(f);
    return *reinterpret_cast<ushort*>(&h);
}

// ---------------------------------------------------------------------------
// Convert hidden -> bf16 and (hidden+pos) -> bf16 in one pass.
// ---------------------------------------------------------------------------
__global__ void prep_acts(const float4* __restrict__ h, const float4* __restrict__ p,
                          ushort4* __restrict__ hb, ushort4* __restrict__ hsb, int n4) {
    int i = blockIdx.x * blockDim.x + threadIdx.x;
    int stride = gridDim.x * blockDim.x;
    for (; i < n4; i += stride) {
        float4 a = h[i], b = p[i];
        ushort4 ua, us;
        ua.x = f2b(a.x); ua.y = f2b(a.y); ua.z = f2b(a.z); ua.w = f2b(a.w);
        us.x = f2b(a.x + b.x); us.y = f2b(a.y + b.y);
        us.z = f2b(a.z + b.z); us.w = f2b(a.w + b.w);
        hb[i] = ua;
        hsb[i] = us;
    }
}

// ---------------------------------------------------------------------------
// Transpose all 4 weight matrices (K=256 each) into Wt[800][256] bf16.
// Rows: [0,256)=Wv, [256,448)=Wo, [448,544)=Wa, [544,800)=Wout.
// One block per output row; thread = k.
// ---------------------------------------------------------------------------
__global__ __launch_bounds__(256) void prep_w(
    const float* __restrict__ Wv, const float* __restrict__ Wo,
    const float* __restrict__ Wa, const float* __restrict__ Wout,
    ushort* __restrict__ Wt) {
    int row = blockIdx.x;
    int k = threadIdx.x;
    const float* src;
    int N, n;
    if (row < 256)      { src = Wv;   N = 256; n = row; }
    else if (row < 448) { src = Wo;   N = 192; n = row - 256; }
    else if (row < 544) { src = Wa;   N = 96;  n = row - 448; }
    else                { src = Wout; N = 256; n = row - 544; }
    float v = src[(size_t)k * N + n];
    Wt[(size_t)row * 256 + k] = f2b(v);
}

// ---------------------------------------------------------------------------
// bf16 MFMA GEMM: C[M,N] = A[M,K]@W[K,N] + bias  (A bf16 [M][K], Wt bf16 [N][K])
// BM=128, BN=64, BK=32. 256 threads = 4 waves in 2x2; wave tile 64x32 via
// 4x2 fragments of mfma_f32_16x16x32_bf16. fp32 accumulate, fp32 C + bias.
// M % 128 == 0 assumed; N guarded.
// ---------------------------------------------------------------------------
__global__ __launch_bounds__(256) void gemm_mfma(
    const ushort* __restrict__ A, const ushort* __restrict__ Wt,
    const float* __restrict__ bias, float* __restrict__ C,
    int M, int N, int K) {
    const int BM = 128, BN = 64, BK = 32, PK = 40;   // PK: padded LDS row (elems)
    __shared__ ushort As[BM][PK];
    __shared__ ushort Bs[BN][PK];
    int bm = blockIdx.y * BM;
    int bn = blockIdx.x * BN;
    int tid = threadIdx.x;
    int lane = tid & 63;
    int wid = tid >> 6;
    int wr = wid >> 1, wc = wid & 1;     // 2x2 wave grid
    int lr = lane & 15;                  // row-in-frag (A) / col (B,C)
    int kg = lane >> 4;                  // k-group 0..3

    f32x4 acc[4][2] = {};

    for (int k0 = 0; k0 < K; k0 += BK) {
        // stage A: 128 rows x 32 bf16; 512 chunks of 8 bf16 (16B)
        #pragma unroll
        for (int c = 0; c < 2; c++) {
            int e = tid + 256 * c;
            int row = e >> 2, q = e & 3;
            const ushort* src = A + (size_t)(bm + row) * K + k0 + 8 * q;
            *(bf16x8*)&As[row][8 * q] = *(const bf16x8*)src;
        }
        // stage B: 64 rows x 32 bf16; 256 chunks
        {
            int row = tid >> 2, q = tid & 3;
            int gn = bn + row;
            bf16x8 v = {0, 0, 0, 0, 0, 0, 0, 0};
            if (gn < N) v = *(const bf16x8*)(Wt + (size_t)gn * K + k0 + 8 * q);
            *(bf16x8*)&Bs[row][8 * q] = v;
        }
        __syncthreads();
        bf16x8 af[4], bfr[2];
        #pragma unroll
        for (int mf = 0; mf < 4; mf++)
            af[mf] = *(bf16x8*)&As[wr * 64 + mf * 16 + lr][kg * 8];
        #pragma unroll
        for (int nf = 0; nf < 2; nf++)
            bfr[nf] = *(bf16x8*)&Bs[wc * 32 + nf * 16 + lr][kg * 8];
        #pragma unroll
        for (int mf = 0; mf < 4; mf++)
            #pragma unroll
            for (int nf = 0; nf < 2; nf++)
                acc[mf][nf] = __builtin_amdgcn_mfma_f32_16x16x32_bf16(
                    af[mf], bfr[nf], acc[mf][nf], 0, 0, 0);
        __syncthreads();
    }

    // epilogue: C[row][col] = acc + bias[col]
    #pragma unroll
    for (int nf = 0; nf < 2; nf++) {
        int gc = bn + wc * 32 + nf * 16 + lr;
        if (gc >= N) continue;
        float bv = bias[gc];
        #pragma unroll
        for (int mf = 0; mf < 4; mf++) {
            int gr0 = bm + wr * 64 + mf * 16 + kg * 4;
            #pragma unroll
            for (int r = 0; r < 4; r++) {
                C[(size_t)(gr0 + r) * N + gc] = acc[mf][nf][r] + bv;
            }
        }
    }
}

// ---------------------------------------------------------------------------
// Softmax over 12 logits per (b,q,h). One thread each.
// ---------------------------------------------------------------------------
__global__ void softmax12(const float* __restrict__ logits, float* __restrict__ attn,
                          int total) {
    int i = blockIdx.x * blockDim.x + threadIdx.x;
    if (i >= total) return;
    const float* p = logits + (size_t)i * 12;
    float m = -INFINITY;
    float v[12];
    #pragma unroll
    for (int j = 0; j < 12; j++) { v[j] = p[j]; m = fmaxf(m, v[j]); }
    float s = 0.f;
    #pragma unroll
    for (int j = 0; j < 12; j++) { v[j] = expf(v[j] - m); s += v[j]; }
    float inv = 1.0f / s;
    float* o = attn + (size_t)i * 12;
    #pragma unroll
    for (int j = 0; j < 12; j++) o[j] = v[j] * inv;
}

// ---------------------------------------------------------------------------
// Deformable sampling, vectorized over channels; writes bf16 `sampled`.
// 256 threads/block = 4 queries; each wave = one query:
//   lane = h*8 + d4  (h in 0..7 heads, d4 in 0..7 float4 channel-groups)
// ---------------------------------------------------------------------------
__global__ __launch_bounds__(256) void msda_sample_v2(
    const float4* __restrict__ value, const float* __restrict__ off,
    const float* __restrict__ attn, const float* __restrict__ refp,
    ushort4* __restrict__ out) {
    int wave = threadIdx.x >> 6;
    int lane = threadIdx.x & 63;
    int bq = blockIdx.x * 4 + wave;
    int h = lane >> 3;
    int d4 = lane & 7;
    int b = bq / SEQ;

    const float* offp = off + (size_t)bq * 192 + h * 24;
    const float* ap   = attn + (size_t)bq * 96 + h * 12;
    const float* rp   = refp + (size_t)bq * 6;
    const float4* vbase = value + ((size_t)b * SEQ) * 64 + h * 8 + d4;

    const int Hs[3] = {64, 32, 16};
    const int st[3] = {0, 4096, 5120};

    float4 acc = make_float4(0.f, 0.f, 0.f, 0.f);
    #pragma unroll
    for (int l = 0; l < 3; l++) {
        int Wl = Hs[l], Hl = Hs[l];
        float fW = (float)Wl, fH = (float)Hl;
        float rxW = rp[l * 2 + 0] * fW;
        float ryH = rp[l * 2 + 1] * fH;
        const float4* vl = vbase + (size_t)st[l] * 64;
        #pragma unroll
        for (int p = 0; p < 4; p++) {
            float aw = ap[l * 4 + p];
            float ox = offp[l * 8 + p * 2 + 0];
            float oy = offp[l * 8 + p * 2 + 1];
            float x = rxW + ox - 0.5f;
            float y = ryH + oy - 0.5f;
            float x0f = floorf(x), y0f = floorf(y);
            float wx = x - x0f, wy = y - y0f;
            int x0 = (int)x0f, y0 = (int)y0f;
            int x1 = x0 + 1, y1 = y0 + 1;
            float vx0 = (x0 >= 0 && x0 < Wl) ? 1.f : 0.f;
            float vx1 = (x1 >= 0 && x1 < Wl) ? 1.f : 0.f;
            float vy0 = (y0 >= 0 && y0 < Hl) ? 1.f : 0.f;
            float vy1 = (y1 >= 0 && y1 < Hl) ? 1.f : 0.f;
            int xc0 = min(max(x0, 0), Wl - 1);
            int xc1 = min(max(x1, 0), Wl - 1);
            int yc0 = min(max(y0, 0), Hl - 1);
            int yc1 = min(max(y1, 0), Hl - 1);
            float w00 = aw * (1.f - wx) * (1.f - wy) * vx0 * vy0;
            float w01 = aw * wx * (1.f - wy) * vx1 * vy0;
            float w10 = aw * (1.f - wx) * wy * vx0 * vy1;
            float w11 = aw * wx * wy * vx1 * vy1;
            float4 t00 = vl[(size_t)(yc0 * Wl + xc0) * 64];
            float4 t01 = vl[(size_t)(yc0 * Wl + xc1) * 64];
            float4 t10 = vl[(size_t)(yc1 * Wl + xc0) * 64];
            float4 t11 = vl[(size_t)(yc1 * Wl + xc1) * 64];
            acc.x = fmaf(w00, t00.x, fmaf(w01, t01.x, fmaf(w10, t10.x, fmaf(w11, t11.x, acc.x))));
            acc.y = fmaf(w00, t00.y, fmaf(w01, t01.y, fmaf(w10, t10.y, fmaf(w11, t11.y, acc.y))));
            acc.z = fmaf(w00, t00.z, fmaf(w01, t01.z, fmaf(w10, t10.z, fmaf(w11, t11.z, acc.z))));
            acc.w = fmaf(w00, t00.w, fmaf(w01, t01.w, fmaf(w10, t10.w, fmaf(w11, t11.w, acc.w))));
        }
    }
    ushort4 o;
    o.x = f2b(acc.x); o.y = f2b(acc.y); o.z = f2b(acc.z); o.w = f2b(acc.w);
    out[(size_t)bq * 64 + h * 8 + d4] = o;
}

// ---------------------------------------------------------------------------
extern "C" void kernel_launch(void* const* d_in, const int* in_sizes, int n_in,
                              void* d_out, int out_size, void* d_ws, size_t ws_size,
                              hipStream_t stream) {
    const float* hidden = (const float*)d_in[0];
    const float* pos    = (const float*)d_in[1];
    const float* refp   = (const float*)d_in[2];
    const float* Wv     = (const float*)d_in[3];
    const float* bv     = (const float*)d_in[4];
    const float* Wo     = (const float*)d_in[5];
    const float* bo     = (const float*)d_in[6];
    const float* Wa     = (const float*)d_in[7];
    const float* ba     = (const float*)d_in[8];
    const float* Wout   = (const float*)d_in[9];
    const float* bout   = (const float*)d_in[10];

    float* out      = (float*)d_out;                       // (B,SEQ,256)
    float* attn_out = out + (size_t)BB * SEQ * DD;         // (B,SEQ,NH,NL,NP)

    const size_t BSD = (size_t)BB * SEQ * DD;              // 5,505,024
    float* ws      = (float*)d_ws;
    float* value   = ws;                                   // fp32 B*SEQ*256
    float* offbuf  = value + BSD;                          // fp32 B*SEQ*192
    float* logits  = offbuf + (size_t)BB * SEQ * 192;      // fp32 B*SEQ*96
    ushort* hb     = (ushort*)(logits + (size_t)BB * SEQ * 96);  // bf16 B*SEQ*256
    ushort* hsb    = hb + BSD;                             // bf16 B*SEQ*256
    ushort* sampb  = hsb + BSD;                            // bf16 B*SEQ*256
    ushort* Wt     = sampb + BSD;                          // bf16 [800][256]

    // 1. prep: hidden->bf16, hidden+pos->bf16
    {
        int n4 = (int)(BSD / 4);
        prep_acts<<<2048, 256, 0, stream>>>((const float4*)hidden, (const float4*)pos,
                                            (ushort4*)hb, (ushort4*)hsb, n4);
    }
    // 2. prep: transpose weights to bf16 [N][K]
    prep_w<<<800, 256, 0, stream>>>(Wv, Wo, Wa, Wout, Wt);

    const ushort* Wv_t   = Wt;
    const ushort* Wo_t   = Wt + (size_t)256 * 256;
    const ushort* Wa_t   = Wt + (size_t)448 * 256;
    const ushort* Wout_t = Wt + (size_t)544 * 256;

    // 3. value = hidden @ Wv + bv
    {
        dim3 grid(DD / 64, MTOT / 128);
        gemm_mfma<<<grid, 256, 0, stream>>>(hb, Wv_t, bv, value, MTOT, DD, DD);
    }
    // 4. off = hs @ Wo + bo  (N=192)
    {
        dim3 grid(192 / 64, MTOT / 128);
        gemm_mfma<<<grid, 256, 0, stream>>>(hsb, Wo_t, bo, offbuf, MTOT, 192, DD);
    }
    // 5. logits = hs @ Wa + ba  (N=96 -> 2 col-blocks, guarded)
    {
        dim3 grid(2, MTOT / 128);
        gemm_mfma<<<grid, 256, 0, stream>>>(hsb, Wa_t, ba, logits, MTOT, 96, DD);
    }
    // 6. softmax over 12 -> attn output region of d_out
    {
        int total = BB * SEQ * NH;
        softmax12<<<(total + 255) / 256, 256, 0, stream>>>(logits, attn_out, total);
    }
    // 7. deformable bilinear sampling -> sampled bf16
    {
        msda_sample_v2<<<MTOT / 4, 256, 0, stream>>>((const float4*)value, offbuf,
                                                     attn_out, refp, (ushort4*)sampb);
    }
    // 8. out = sampled @ Wout + bout -> d_out
    {
        dim3 grid(DD / 64, MTOT / 128);
        gemm_mfma<<<grid, 256, 0, stream>>>(sampb, Wout_t, bout, out, MTOT, DD, DD);
    }
}

// Round 4
// 103.847 us; speedup vs baseline: 4.0799x; 1.1235x over previous
//
#include <hip/hip_runtime.h>
#include <hip/hip_bf16.h>
#include <math.h>

// Problem constants (Mask2Former pixel decoder / MS-deformable attention)
#define BB 4
#define SEQ 5376
#define DD 256
#define NH 8
#define NL 3
#define NP 4
#define DH 32
#define MTOT (BB * SEQ)          // 21504 rows for all GEMMs

typedef __attribute__((ext_vector_type(8))) short bf16x8;
typedef __attribute__((ext_vector_type(4))) float f32x4;

__device__ __forceinline__ ushort f2b(float f) {
    __hip_bfloat16 h = __float2bfloat16(f);
    return *reinterpret_cast<ushort*>(&h);
}

// ---------------------------------------------------------------------------
// Convert hidden -> bf16 and (hidden+pos) -> bf16 in one pass.
// ---------------------------------------------------------------------------
__global__ void prep_acts(const float4* __restrict__ h, const float4* __restrict__ p,
                          ushort4* __restrict__ hb, ushort4* __restrict__ hsb, int n4) {
    int i = blockIdx.x * blockDim.x + threadIdx.x;
    int stride = gridDim.x * blockDim.x;
    for (; i < n4; i += stride) {
        float4 a = h[i], b = p[i];
        ushort4 ua, us;
        ua.x = f2b(a.x); ua.y = f2b(a.y); ua.z = f2b(a.z); ua.w = f2b(a.w);
        us.x = f2b(a.x + b.x); us.y = f2b(a.y + b.y);
        us.z = f2b(a.z + b.z); us.w = f2b(a.w + b.w);
        hb[i] = ua;
        hsb[i] = us;
    }
}

// ---------------------------------------------------------------------------
// Transpose all 4 weight matrices (K=256 each) into Wt[800][256] bf16.
// Rows: [0,256)=Wv, [256,448)=Wo, [448,544)=Wa, [544,800)=Wout.
// Block 800: build combined bias for the merged off+logits GEMM (288 floats).
// ---------------------------------------------------------------------------
__global__ __launch_bounds__(256) void prep_w(
    const float* __restrict__ Wv, const float* __restrict__ Wo,
    const float* __restrict__ Wa, const float* __restrict__ Wout,
    const float* __restrict__ bo, const float* __restrict__ ba,
    ushort* __restrict__ Wt, float* __restrict__ bcomb) {
    int row = blockIdx.x;
    int k = threadIdx.x;
    if (row == 800) {
        for (int i = k; i < 288; i += 256)
            bcomb[i] = (i < 192) ? bo[i] : ba[i - 192];
        return;
    }
    const float* src;
    int N, n;
    if (row < 256)      { src = Wv;   N = 256; n = row; }
    else if (row < 448) { src = Wo;   N = 192; n = row - 256; }
    else if (row < 544) { src = Wa;   N = 96;  n = row - 448; }
    else                { src = Wout; N = 256; n = row - 544; }
    float v = src[(size_t)k * N + n];
    Wt[(size_t)row * 256 + k] = f2b(v);
}

// ---------------------------------------------------------------------------
// bf16 MFMA GEMM: C[M,N] = A[M,K]@W[K,N] + bias  (A bf16 [M][K], Wt bf16 [N][K])
// BM=128, BN=64, BK=32. 256 threads = 4 waves 2x2; wave tile 64x32 via 4x2
// fragments of mfma_f32_16x16x32_bf16. OBF: write bf16 output, else fp32.
// ---------------------------------------------------------------------------
template<bool OBF>
__global__ __launch_bounds__(256) void gemm_mfma(
    const ushort* __restrict__ A, const ushort* __restrict__ Wt,
    const float* __restrict__ bias, void* __restrict__ Cout,
    int M, int N, int K) {
    const int BM = 128, BN = 64, BK = 32, PK = 40;   // PK: padded LDS row (elems)
    __shared__ ushort As[BM][PK];
    __shared__ ushort Bs[BN][PK];
    int bm = blockIdx.y * BM;
    int bn = blockIdx.x * BN;
    int tid = threadIdx.x;
    int lane = tid & 63;
    int wid = tid >> 6;
    int wr = wid >> 1, wc = wid & 1;     // 2x2 wave grid
    int lr = lane & 15;                  // row-in-frag (A) / col (B,C)
    int kg = lane >> 4;                  // k-group 0..3

    f32x4 acc[4][2] = {};

    for (int k0 = 0; k0 < K; k0 += BK) {
        // stage A: 128 rows x 32 bf16; 512 chunks of 8 bf16 (16B)
        #pragma unroll
        for (int c = 0; c < 2; c++) {
            int e = tid + 256 * c;
            int row = e >> 2, q = e & 3;
            const ushort* src = A + (size_t)(bm + row) * K + k0 + 8 * q;
            *(bf16x8*)&As[row][8 * q] = *(const bf16x8*)src;
        }
        // stage B: 64 rows x 32 bf16; 256 chunks
        {
            int row = tid >> 2, q = tid & 3;
            int gn = bn + row;
            bf16x8 v = {0, 0, 0, 0, 0, 0, 0, 0};
            if (gn < N) v = *(const bf16x8*)(Wt + (size_t)gn * K + k0 + 8 * q);
            *(bf16x8*)&Bs[row][8 * q] = v;
        }
        __syncthreads();
        bf16x8 af[4], bfr[2];
        #pragma unroll
        for (int mf = 0; mf < 4; mf++)
            af[mf] = *(bf16x8*)&As[wr * 64 + mf * 16 + lr][kg * 8];
        #pragma unroll
        for (int nf = 0; nf < 2; nf++)
            bfr[nf] = *(bf16x8*)&Bs[wc * 32 + nf * 16 + lr][kg * 8];
        #pragma unroll
        for (int mf = 0; mf < 4; mf++)
            #pragma unroll
            for (int nf = 0; nf < 2; nf++)
                acc[mf][nf] = __builtin_amdgcn_mfma_f32_16x16x32_bf16(
                    af[mf], bfr[nf], acc[mf][nf], 0, 0, 0);
        __syncthreads();
    }

    // epilogue: C[row][col] = acc + bias[col]
    #pragma unroll
    for (int nf = 0; nf < 2; nf++) {
        int gc = bn + wc * 32 + nf * 16 + lr;
        if (gc >= N) continue;
        float bv = bias[gc];
        #pragma unroll
        for (int mf = 0; mf < 4; mf++) {
            int gr0 = bm + wr * 64 + mf * 16 + kg * 4;
            #pragma unroll
            for (int r = 0; r < 4; r++) {
                float v = acc[mf][nf][r] + bv;
                if constexpr (OBF)
                    ((ushort*)Cout)[(size_t)(gr0 + r) * N + gc] = f2b(v);
                else
                    ((float*)Cout)[(size_t)(gr0 + r) * N + gc] = v;
            }
        }
    }
}

// ---------------------------------------------------------------------------
// Softmax over 12 logits per (b,q,h); logits live in comb[row][192..288).
// ---------------------------------------------------------------------------
__global__ void softmax12(const float* __restrict__ comb, float* __restrict__ attn,
                          int total) {
    int i = blockIdx.x * blockDim.x + threadIdx.x;
    if (i >= total) return;
    int bq = i >> 3, h = i & 7;
    const float* p = comb + (size_t)bq * 288 + 192 + h * 12;
    float m = -INFINITY;
    float v[12];
    #pragma unroll
    for (int j = 0; j < 12; j++) { v[j] = p[j]; m = fmaxf(m, v[j]); }
    float s = 0.f;
    #pragma unroll
    for (int j = 0; j < 12; j++) { v[j] = expf(v[j] - m); s += v[j]; }
    float inv = 1.0f / s;
    float* o = attn + (size_t)i * 12;
    #pragma unroll
    for (int j = 0; j < 12; j++) o[j] = v[j] * inv;
}

// ---------------------------------------------------------------------------
// Deformable sampling v3: LDS tap table + bf16 value.
// Block = 4 queries (4 waves). Phase 1: 384 taps -> {4 idx, 4 weights} in LDS.
// Phase 2: wave q, lane = h*8+d4; per tap: 2 ds_read_b128 (broadcast within
// head) + 4x 8B bf16 gathers + 16 fma. Output bf16 (feeds final GEMM).
// ---------------------------------------------------------------------------
__global__ __launch_bounds__(256) void msda_sample_v3(
    const ushort* __restrict__ value, const float* __restrict__ comb,
    const float* __restrict__ attn, const float* __restrict__ refp,
    ushort* __restrict__ out) {
    __shared__ int4   s_idx[4][8][13];   // [q][h][lp], pad 12->13: conflict-free
    __shared__ float4 s_w[4][8][13];
    int tid = threadIdx.x;
    int bq0 = blockIdx.x * 4;

    for (int t = tid; t < 384; t += 256) {
        int q = t / 96;
        int r = t - q * 96;          // 0..95 = h*12 + lp
        int h = r / 12;
        int lp = r - h * 12;         // l*4 + p
        int l = lp >> 2;
        int bq = bq0 + q;
        int b = bq / SEQ;
        int Wl = 64 >> l;
        float fW = (float)Wl;
        float rx = refp[(size_t)bq * 6 + 2 * l];
        float ry = refp[(size_t)bq * 6 + 2 * l + 1];
        float ox = comb[(size_t)bq * 288 + h * 24 + lp * 2];
        float oy = comb[(size_t)bq * 288 + h * 24 + lp * 2 + 1];
        float aw = attn[(size_t)bq * 96 + r];
        float x = rx * fW + ox - 0.5f;
        float y = ry * fW + oy - 0.5f;
        float x0f = floorf(x), y0f = floorf(y);
        float wx = x - x0f, wy = y - y0f;
        int x0 = (int)x0f, y0 = (int)y0f;
        int x1 = x0 + 1, y1 = y0 + 1;
        float vx0 = (x0 >= 0 && x0 < Wl) ? 1.f : 0.f;
        float vx1 = (x1 >= 0 && x1 < Wl) ? 1.f : 0.f;
        float vy0 = (y0 >= 0 && y0 < Wl) ? 1.f : 0.f;   // square levels: H==W
        float vy1 = (y1 >= 0 && y1 < Wl) ? 1.f : 0.f;
        int xc0 = min(max(x0, 0), Wl - 1);
        int xc1 = min(max(x1, 0), Wl - 1);
        int yc0 = min(max(y0, 0), Wl - 1);
        int yc1 = min(max(y1, 0), Wl - 1);
        int st = (l == 0) ? 0 : ((l == 1) ? 4096 : 5120);
        int rowbase = b * SEQ + st;
        s_idx[q][h][lp] = make_int4((rowbase + yc0 * Wl + xc0) << 8,
                                    (rowbase + yc0 * Wl + xc1) << 8,
                                    (rowbase + yc1 * Wl + xc0) << 8,
                                    (rowbase + yc1 * Wl + xc1) << 8);
        s_w[q][h][lp] = make_float4(aw * (1.f - wx) * (1.f - wy) * vx0 * vy0,
                                    aw * wx * (1.f - wy) * vx1 * vy0,
                                    aw * (1.f - wx) * wy * vx0 * vy1,
                                    aw * wx * wy * vx1 * vy1);
    }
    __syncthreads();

    int wave = tid >> 6, lane = tid & 63;
    int h = lane >> 3, d4 = lane & 7;
    int bq = bq0 + wave;
    int ch0 = h * 32 + d4 * 4;
    const ushort* vb = value + ch0;
    float4 acc = make_float4(0.f, 0.f, 0.f, 0.f);
    #pragma unroll
    for (int lp = 0; lp < 12; lp++) {
        int4 ii = s_idx[wave][h][lp];
        float4 ww = s_w[wave][h][lp];
        uint2 u0 = *(const uint2*)(vb + ii.x);
        uint2 u1 = *(const uint2*)(vb + ii.y);
        uint2 u2 = *(const uint2*)(vb + ii.z);
        uint2 u3 = *(const uint2*)(vb + ii.w);
        acc.x = fmaf(ww.x, __uint_as_float(u0.x << 16), acc.x);
        acc.y = fmaf(ww.x, __uint_as_float(u0.x & 0xffff0000u), acc.y);
        acc.z = fmaf(ww.x, __uint_as_float(u0.y << 16), acc.z);
        acc.w = fmaf(ww.x, __uint_as_float(u0.y & 0xffff0000u), acc.w);
        acc.x = fmaf(ww.y, __uint_as_float(u1.x << 16), acc.x);
        acc.y = fmaf(ww.y, __uint_as_float(u1.x & 0xffff0000u), acc.y);
        acc.z = fmaf(ww.y, __uint_as_float(u1.y << 16), acc.z);
        acc.w = fmaf(ww.y, __uint_as_float(u1.y & 0xffff0000u), acc.w);
        acc.x = fmaf(ww.z, __uint_as_float(u2.x << 16), acc.x);
        acc.y = fmaf(ww.z, __uint_as_float(u2.x & 0xffff0000u), acc.y);
        acc.z = fmaf(ww.z, __uint_as_float(u2.y << 16), acc.z);
        acc.w = fmaf(ww.z, __uint_as_float(u2.y & 0xffff0000u), acc.w);
        acc.x = fmaf(ww.w, __uint_as_float(u3.x << 16), acc.x);
        acc.y = fmaf(ww.w, __uint_as_float(u3.x & 0xffff0000u), acc.y);
        acc.z = fmaf(ww.w, __uint_as_float(u3.y << 16), acc.z);
        acc.w = fmaf(ww.w, __uint_as_float(u3.y & 0xffff0000u), acc.w);
    }
    ushort4 o;
    o.x = f2b(acc.x); o.y = f2b(acc.y); o.z = f2b(acc.z); o.w = f2b(acc.w);
    *(ushort4*)(out + (size_t)bq * 256 + ch0) = o;
}

// ---------------------------------------------------------------------------
extern "C" void kernel_launch(void* const* d_in, const int* in_sizes, int n_in,
                              void* d_out, int out_size, void* d_ws, size_t ws_size,
                              hipStream_t stream) {
    const float* hidden = (const float*)d_in[0];
    const float* pos    = (const float*)d_in[1];
    const float* refp   = (const float*)d_in[2];
    const float* Wv     = (const float*)d_in[3];
    const float* bv     = (const float*)d_in[4];
    const float* Wo     = (const float*)d_in[5];
    const float* bo     = (const float*)d_in[6];
    const float* Wa     = (const float*)d_in[7];
    const float* ba     = (const float*)d_in[8];
    const float* Wout   = (const float*)d_in[9];
    const float* bout   = (const float*)d_in[10];

    float* out      = (float*)d_out;                       // (B,SEQ,256)
    float* attn_out = out + (size_t)BB * SEQ * DD;         // (B,SEQ,NH,NL,NP)

    const size_t BSD = (size_t)BB * SEQ * DD;              // 5,505,024
    char* w = (char*)d_ws;
    ushort* value_bf = (ushort*)w;  w += BSD * 2;                 // bf16 value
    float*  comb     = (float*)w;   w += (size_t)MTOT * 288 * 4;  // off|logits
    ushort* sampb    = (ushort*)w;  w += BSD * 2;                 // bf16 sampled
    ushort* hb       = (ushort*)w;  w += BSD * 2;                 // bf16 hidden
    ushort* hsb      = (ushort*)w;  w += BSD * 2;                 // bf16 hidden+pos
    ushort* Wt       = (ushort*)w;  w += (size_t)800 * 256 * 2;   // bf16 weights^T
    float*  bcomb    = (float*)w;                                 // 288 bias

    // 1. prep: hidden->bf16, hidden+pos->bf16
    {
        int n4 = (int)(BSD / 4);
        prep_acts<<<2048, 256, 0, stream>>>((const float4*)hidden, (const float4*)pos,
                                            (ushort4*)hb, (ushort4*)hsb, n4);
    }
    // 2. prep: transpose weights to bf16 [N][K] + combined bias
    prep_w<<<801, 256, 0, stream>>>(Wv, Wo, Wa, Wout, bo, ba, Wt, bcomb);

    const ushort* Wv_t    = Wt;
    const ushort* Wcomb_t = Wt + (size_t)256 * 256;   // rows: 192 Wo + 96 Wa
    const ushort* Wout_t  = Wt + (size_t)544 * 256;

    // 3. value = hidden @ Wv + bv  -> bf16
    {
        dim3 grid(DD / 64, MTOT / 128);
        gemm_mfma<true><<<grid, 256, 0, stream>>>(hb, Wv_t, bv, value_bf, MTOT, DD, DD);
    }
    // 4. comb = hs @ [Wo|Wa] + [bo|ba]  (N=288, guarded last block)
    {
        dim3 grid(5, MTOT / 128);
        gemm_mfma<false><<<grid, 256, 0, stream>>>(hsb, Wcomb_t, bcomb, comb, MTOT, 288, DD);
    }
    // 5. softmax over 12 -> attn output region of d_out
    {
        int total = BB * SEQ * NH;
        softmax12<<<(total + 255) / 256, 256, 0, stream>>>(comb, attn_out, total);
    }
    // 6. deformable bilinear sampling -> sampled bf16
    {
        msda_sample_v3<<<MTOT / 4, 256, 0, stream>>>(value_bf, comb, attn_out, refp, sampb);
    }
    // 7. out = sampled @ Wout + bout -> d_out
    {
        dim3 grid(DD / 64, MTOT / 128);
        gemm_mfma<false><<<grid, 256, 0, stream>>>(sampb, Wout_t, bout, out, MTOT, DD, DD);
    }
}